// Round 4
// baseline (3118.827 us; speedup 1.0000x reference)
//
#include <hip/hip_runtime.h>
#include <math.h>

namespace {
constexpr int   NG    = 64;
constexpr int   GC    = NG * NG * NG;
constexpr int   BOUND = 3;
constexpr float DXf    = 1.0f / 64.0f;
constexpr float INV_DX = 64.0f;
constexpr float DTf    = 5e-4f;
constexpr double P_VOL_D = (0.5 / 64.0) * (0.5 / 64.0) * (0.5 / 64.0);
constexpr float P_MASS_F = (float)(P_VOL_D * 1000.0);
constexpr float AFFINE_SCALE = (float)(-5e-4 * P_VOL_D * 4.0 * 64.0 * 64.0);
constexpr float D_INV  = 4.0f * 64.0f * 64.0f;   // 16384
constexpr float GRAV_Y = -9.8f;

__device__ __forceinline__ void atom_add_f32(float* p, float v) {
    unsafeAtomicAdd(p, v);   // hw global_atomic_add_f32, fire-and-forget
}

__device__ __forceinline__ void weights_of(float fx0, float fx1, float fx2, float w[3][3]) {
    w[0][0] = 0.5f*(1.5f-fx0)*(1.5f-fx0); w[0][1] = 0.5f*(1.5f-fx1)*(1.5f-fx1); w[0][2] = 0.5f*(1.5f-fx2)*(1.5f-fx2);
    w[1][0] = 0.75f-(fx0-1.0f)*(fx0-1.0f); w[1][1] = 0.75f-(fx1-1.0f)*(fx1-1.0f); w[1][2] = 0.75f-(fx2-1.0f)*(fx2-1.0f);
    w[2][0] = 0.5f*(fx0-0.5f)*(fx0-0.5f); w[2][1] = 0.5f*(fx1-0.5f)*(fx1-0.5f); w[2][2] = 0.5f*(fx2-0.5f)*(fx2-0.5f);
}

// quadratic B-spline weight at signed offset u; 0 outside |u|<1.5.
// Bit-exact equal to the reference per-offset formulas for u = fx - o.
__device__ __forceinline__ float bspline_w(float u) {
    float au = fabsf(u);
    float a  = 1.5f - au;
    float w  = (au < 0.5f) ? (0.75f - u * u) : (0.5f * a * a);
    return (au < 1.5f) ? w : 0.f;
}
}

// ---------------- pass 1: histogram particles into CELLS (262144 bins) -------
__global__ __launch_bounds__(256) void count_kernel(const float* __restrict__ x,
                                                    int* __restrict__ cnt, int n)
{
    int p = blockIdx.x * 256 + threadIdx.x;
    if (p >= n) return;
    float u0 = x[3*p] * INV_DX, u1 = x[3*p+1] * INV_DX, u2 = x[3*p+2] * INV_DX;
    int b0 = (int)floorf(u0 - 0.5f), b1 = (int)floorf(u1 - 0.5f), b2 = (int)floorf(u2 - 0.5f);
    if ((unsigned)b0 >= 64u || (unsigned)b1 >= 64u || (unsigned)b2 >= 64u) return;
    atomicAdd(&cnt[((b0 << 6) + b1) * 64 + b2], 1);
}

// ---------------- pass 2a: per-256-block exclusive scan, block totals to aux --
__global__ __launch_bounds__(256) void scanA(const int* __restrict__ cnt,
                                             int* __restrict__ start,
                                             int* __restrict__ aux)
{
    __shared__ int sh[256];
    int tid = threadIdx.x;
    int i = blockIdx.x * 256 + tid;
    int v = cnt[i];
    sh[tid] = v;
    __syncthreads();
    for (int off = 1; off < 256; off <<= 1) {
        int t = (tid >= off) ? sh[tid - off] : 0;
        __syncthreads();
        sh[tid] += t;
        __syncthreads();
    }
    start[i] = sh[tid] - v;                 // block-local exclusive
    if (tid == 255) aux[blockIdx.x] = sh[255];
}

// ---------------- pass 2b: scan the 1024 block totals (single block) ---------
__global__ __launch_bounds__(256) void scanB(int* __restrict__ aux,
                                             int* __restrict__ start)
{
    __shared__ int partial[256];
    int tid = threadIdx.x;
    int local[4];
    int s = 0;
#pragma unroll
    for (int i = 0; i < 4; ++i) { local[i] = s; s += aux[tid * 4 + i]; }
    partial[tid] = s;
    __syncthreads();
    for (int off = 1; off < 256; off <<= 1) {
        int v = (tid >= off) ? partial[tid - off] : 0;
        __syncthreads();
        partial[tid] += v;
        __syncthreads();
    }
    int base = (tid > 0) ? partial[tid - 1] : 0;
#pragma unroll
    for (int i = 0; i < 4; ++i) aux[tid * 4 + i] = base + local[i];
    if (tid == 255) start[GC] = partial[255];   // grand total sentinel
}

// ---------------- pass 2c: add block offsets, emit start & cursor ------------
__global__ __launch_bounds__(256) void scanC(int* __restrict__ start,
                                             const int* __restrict__ aux,
                                             int* __restrict__ cursor)
{
    int i = blockIdx.x * 256 + threadIdx.x;
    int v = start[i] + aux[blockIdx.x];
    start[i] = v;
    cursor[i] = v;
}

// ---------------- pass 3: reorder — coalesced read, precompute, payload write
// payload record (64B): [af00,af01,af02,af10][af11,af12,af20,af21][af22,mv0,mv1,mv2][u0,u1,u2,-]
// where u = x*INV_DX is the grid-space position (base+fx combined).
__global__ __launch_bounds__(256) void reorder_kernel(const float* __restrict__ x,
                                                      const float* __restrict__ v,
                                                      const float* __restrict__ C,
                                                      const float* __restrict__ st,
                                                      int* __restrict__ cursor,
                                                      float4* __restrict__ payload, int n)
{
    int p = blockIdx.x * 256 + threadIdx.x;
    if (p >= n) return;

    float u0 = x[3*p] * INV_DX, u1 = x[3*p+1] * INV_DX, u2 = x[3*p+2] * INV_DX;
    int b0 = (int)floorf(u0 - 0.5f), b1 = (int)floorf(u1 - 0.5f), b2 = (int)floorf(u2 - 0.5f);
    if ((unsigned)b0 >= 64u || (unsigned)b1 >= 64u || (unsigned)b2 >= 64u) return;

    float aff[9];
#pragma unroll
    for (int i = 0; i < 9; ++i)
        aff[i] = st[9*p + i] * AFFINE_SCALE + P_MASS_F * C[9*p + i];
    float mv0 = P_MASS_F * v[3*p], mv1 = P_MASS_F * v[3*p+1], mv2 = P_MASS_F * v[3*p+2];

    int pos = atomicAdd(&cursor[((b0 << 6) + b1) * 64 + b2], 1);

    float4* dst = payload + 4 * (size_t)pos;
    dst[0] = make_float4(aff[0], aff[1], aff[2], aff[3]);
    dst[1] = make_float4(aff[4], aff[5], aff[6], aff[7]);
    dst[2] = make_float4(aff[8], mv0, mv1, mv2);
    dst[3] = make_float4(u0, u1, u2, 0.f);
}

// ---------------- pass 4: cell-centric P2G gather — no atomics, no LDS -------
// one thread per grid cell. Cell g gathers particles with base in [g-2,g]^3:
// for each of 9 (o0,o1) rows, the 3 k-neighbors are CONTIGUOUS cell ids, so
// the thread scans one contiguous payload segment per row. Every pair touched
// has nonzero weight (exact 27-cell support; no wasted FLOPs). Grid normalize
// + gravity + boundary are fused here; the cell is owned exclusively -> plain
// float4 store, and the grid array needs no memset.
__global__ __launch_bounds__(256) void p2g_cell(const float4* __restrict__ payload,
                                                const int* __restrict__ start,
                                                float* __restrict__ grid)
{
    int g = blockIdx.x * 256 + threadIdx.x;
    int g0 = g >> 12, g1 = (g >> 6) & 63, g2 = g & 63;
    float fg0 = (float)g0, fg1 = (float)g1, fg2 = (float)g2;

    float acc0 = 0.f, acc1 = 0.f, acc2 = 0.f, acc3 = 0.f;
    int klo = (g2 >= 2) ? g2 - 2 : 0;

#pragma unroll
    for (int o0 = 0; o0 < 3; ++o0) {
        int b0 = g0 - o0;
        if ((unsigned)b0 >= 64u) continue;
#pragma unroll
        for (int o1 = 0; o1 < 3; ++o1) {
            int b1 = g1 - o1;
            if ((unsigned)b1 >= 64u) continue;
            int row = ((b0 << 6) + b1) << 6;
            int s = start[row + klo];
            int e = start[row + g2 + 1];
            for (int idx = s; idx < e; ++idx) {
                const float4* rec = payload + 4 * (size_t)idx;
                float4 r0 = rec[0], r1 = rec[1], r2 = rec[2], r3 = rec[3];
                float u0 = r3.x - fg0, u1 = r3.y - fg1, u2 = r3.z - fg2;
                float w = bspline_w(u0) * bspline_w(u1) * bspline_w(u2);
                float dp0 = -u0 * DXf, dp1 = -u1 * DXf, dp2 = -u2 * DXf;
                acc0 += w * (r2.y + r0.x * dp0 + r0.y * dp1 + r0.z * dp2);
                acc1 += w * (r2.z + r0.w * dp0 + r1.x * dp1 + r1.y * dp2);
                acc2 += w * (r2.w + r1.z * dp0 + r1.w * dp1 + r2.x * dp2);
                acc3 += w * P_MASS_F;
            }
        }
    }

    // fused grid update: normalize, gravity, boundary
    float v0 = 0.f, v1 = 0.f, v2 = 0.f;
    if (acc3 > 0.f) {
        float mm = fmaxf(acc3, 1e-10f);
        v0 = acc0 / mm;
        v1 = acc1 / mm + DTf * GRAV_Y;
        v2 = acc2 / mm;
    }
    if ((g0 < BOUND && v0 < 0.f) || (g0 >= NG - BOUND && v0 > 0.f)) v0 = 0.f;
    if ((g1 < BOUND && v1 < 0.f) || (g1 >= NG - BOUND && v1 > 0.f)) v1 = 0.f;
    if ((g2 < BOUND && v2 < 0.f) || (g2 >= NG - BOUND && v2 > 0.f)) v2 = 0.f;
    ((float4*)grid)[g] = make_float4(v0, v1, v2, acc3);
}

// ---------------- fallback P2G: direct global atomics ----------------
__global__ __launch_bounds__(256) void p2g_naive(const float* __restrict__ x,
                                                 const float* __restrict__ v,
                                                 const float* __restrict__ C,
                                                 const float* __restrict__ st,
                                                 float* __restrict__ grid, int n)
{
    int p = blockIdx.x * 256 + threadIdx.x;
    if (p >= n) return;

    float xp0 = x[3*p], xp1 = x[3*p+1], xp2 = x[3*p+2];
    float u0 = xp0 * INV_DX, u1 = xp1 * INV_DX, u2 = xp2 * INV_DX;
    float b0f = floorf(u0 - 0.5f), b1f = floorf(u1 - 0.5f), b2f = floorf(u2 - 0.5f);
    int base0 = (int)b0f, base1 = (int)b1f, base2 = (int)b2f;
    float fx0 = u0 - b0f, fx1 = u1 - b1f, fx2 = u2 - b2f;

    float w[3][3];
    weights_of(fx0, fx1, fx2, w);

    float aff[3][3];
#pragma unroll
    for (int i = 0; i < 3; ++i)
#pragma unroll
        for (int j = 0; j < 3; ++j)
            aff[i][j] = st[9*p + 3*i + j] * AFFINE_SCALE + P_MASS_F * C[9*p + 3*i + j];

    float mv0 = P_MASS_F * v[3*p], mv1 = P_MASS_F * v[3*p+1], mv2 = P_MASS_F * v[3*p+2];

#pragma unroll
    for (int i = 0; i < 3; ++i) {
        float dp0 = ((float)i - fx0) * DXf;
#pragma unroll
        for (int j = 0; j < 3; ++j) {
            float dp1 = ((float)j - fx1) * DXf;
            float wij = w[i][0] * w[j][1];
            float m0 = mv0 + aff[0][0]*dp0 + aff[0][1]*dp1;
            float m1 = mv1 + aff[1][0]*dp0 + aff[1][1]*dp1;
            float m2 = mv2 + aff[2][0]*dp0 + aff[2][1]*dp1;
            int cellij = ((base0 + i) * NG + (base1 + j)) * NG + base2;
#pragma unroll
            for (int k = 0; k < 3; ++k) {
                float dp2 = ((float)k - fx2) * DXf;
                float wi = wij * w[k][2];
                float* cptr = grid + 4 * (cellij + k);
                atom_add_f32(cptr + 0, wi * (m0 + aff[0][2]*dp2));
                atom_add_f32(cptr + 1, wi * (m1 + aff[1][2]*dp2));
                atom_add_f32(cptr + 2, wi * (m2 + aff[2][2]*dp2));
                atom_add_f32(cptr + 3, wi * P_MASS_F);
            }
        }
    }
}

// ---------------- grid: normalize, gravity, boundary (fallback path only) ----
__global__ __launch_bounds__(256) void grid_kernel(float* __restrict__ grid)
{
    int g = blockIdx.x * 256 + threadIdx.x;
    if (g >= GC) return;
    float4 val = ((const float4*)grid)[g];
    float m = val.w;
    float v0 = 0.f, v1 = 0.f, v2 = 0.f;
    if (m > 0.f) {
        float mm = fmaxf(m, 1e-10f);
        v0 = val.x / mm;
        v1 = val.y / mm + DTf * GRAV_Y;
        v2 = val.z / mm;
    }
    int ci = g >> 12, cj = (g >> 6) & 63, ck = g & 63;
    if ((ci < BOUND && v0 < 0.f) || (ci >= NG - BOUND && v0 > 0.f)) v0 = 0.f;
    if ((cj < BOUND && v1 < 0.f) || (cj >= NG - BOUND && v1 > 0.f)) v1 = 0.f;
    if ((ck < BOUND && v2 < 0.f) || (ck >= NG - BOUND && v2 > 0.f)) v2 = 0.f;
    ((float4*)grid)[g] = make_float4(v0, v1, v2, m);
}

// ---------------- G2P: gather, advect, update C/F ----------------
__global__ __launch_bounds__(256) void g2p_kernel(const float* __restrict__ x,
                                                  const float* __restrict__ F,
                                                  const float* __restrict__ grid,
                                                  float* __restrict__ out_x,
                                                  float* __restrict__ out_v,
                                                  float* __restrict__ out_C,
                                                  float* __restrict__ out_F,
                                                  int n)
{
    int p = blockIdx.x * 256 + threadIdx.x;
    if (p >= n) return;

    float xp0 = x[3*p], xp1 = x[3*p+1], xp2 = x[3*p+2];
    float t0 = xp0 * INV_DX, t1 = xp1 * INV_DX, t2 = xp2 * INV_DX;
    float b0 = floorf(t0 - 0.5f), b1 = floorf(t1 - 0.5f), b2 = floorf(t2 - 0.5f);
    int   base0 = (int)b0, base1 = (int)b1, base2 = (int)b2;
    float fx0 = t0 - b0, fx1 = t1 - b1, fx2 = t2 - b2;

    float w[3][3];
    weights_of(fx0, fx1, fx2, w);

    float vn0 = 0.f, vn1 = 0.f, vn2 = 0.f;
    float Cn[3][3] = {};

#pragma unroll
    for (int i = 0; i < 3; ++i) {
        float dp0 = ((float)i - fx0) * DXf;
#pragma unroll
        for (int j = 0; j < 3; ++j) {
            float dp1 = ((float)j - fx1) * DXf;
            float wij = w[i][0] * w[j][1];
            int cellij = ((base0 + i) * NG + (base1 + j)) * NG + base2;
#pragma unroll
            for (int k = 0; k < 3; ++k) {
                float dp2 = ((float)k - fx2) * DXf;
                float wi = wij * w[k][2];
                float4 gv = ((const float4*)grid)[cellij + k];
                vn0 += wi * gv.x; vn1 += wi * gv.y; vn2 += wi * gv.z;
                float wx = wi * gv.x, wy = wi * gv.y, wz = wi * gv.z;
                Cn[0][0] += wx * dp0; Cn[0][1] += wx * dp1; Cn[0][2] += wx * dp2;
                Cn[1][0] += wy * dp0; Cn[1][1] += wy * dp1; Cn[1][2] += wy * dp2;
                Cn[2][0] += wz * dp0; Cn[2][1] += wz * dp1; Cn[2][2] += wz * dp2;
            }
        }
    }

#pragma unroll
    for (int i = 0; i < 3; ++i)
#pragma unroll
        for (int j = 0; j < 3; ++j)
            Cn[i][j] *= D_INV;

    out_x[3*p]   = xp0 + DTf * vn0;
    out_x[3*p+1] = xp1 + DTf * vn1;
    out_x[3*p+2] = xp2 + DTf * vn2;
    out_v[3*p]   = vn0; out_v[3*p+1] = vn1; out_v[3*p+2] = vn2;

    float Fp[3][3];
#pragma unroll
    for (int i = 0; i < 3; ++i)
#pragma unroll
        for (int j = 0; j < 3; ++j)
            Fp[i][j] = F[9*p + 3*i + j];

#pragma unroll
    for (int i = 0; i < 3; ++i) {
#pragma unroll
        for (int k = 0; k < 3; ++k) {
            float acc = Cn[i][0]*Fp[0][k] + Cn[i][1]*Fp[1][k] + Cn[i][2]*Fp[2][k];
            out_F[9*p + 3*i + k] = Fp[i][k] + DTf * acc;
            out_C[9*p + 3*i + k] = Cn[i][k];
        }
    }
}

extern "C" void kernel_launch(void* const* d_in, const int* in_sizes, int n_in,
                              void* d_out, int out_size, void* d_ws, size_t ws_size,
                              hipStream_t stream)
{
    const float* x  = (const float*)d_in[0];
    const float* v  = (const float*)d_in[1];
    const float* C  = (const float*)d_in[2];
    const float* F  = (const float*)d_in[3];
    const float* st = (const float*)d_in[4];
    int n = in_sizes[0] / 3;

    const size_t grid_bytes = (size_t)GC * 4 * sizeof(float);          // 4 MiB
    // tables live in the dead out-tail [22n, 24n): cnt(GC) + start(GC+1) + cursor(GC) + aux(1024)
    const size_t tab_ints   = 3 * (size_t)GC + 1 + 1024;
    const bool   use_tiled  = ws_size >= grid_bytes &&
                              (size_t)out_size >= 4 * (22 * (size_t)n + tab_ints);

    float* grid = (float*)d_ws;

    float* out  = (float*)d_out;
    float* out_x = out;
    float* out_v = out + 3 * (size_t)n;
    float* out_C = out + 6 * (size_t)n;
    float* out_F = out + 15 * (size_t)n;
    // payload (16 floats/particle) lives in out[6n .. 22n) — dead until g2p overwrites
    float4* payload = (float4*)(out + 6 * (size_t)n);
    int* tab    = (int*)(out + 22 * (size_t)n);
    int* cnt    = tab;                       // GC
    int* tstart = tab + GC;                  // GC + 1
    int* cursor = tab + 2 * GC + 1;          // GC
    int* aux    = tab + 3 * GC + 1;          // 1024

    int pblocks = (n + 255) / 256;

    if (use_tiled) {
        hipMemsetAsync(cnt, 0, (size_t)GC * sizeof(int), stream);
        count_kernel<<<pblocks, 256, 0, stream>>>(x, cnt, n);
        scanA<<<GC / 256, 256, 0, stream>>>(cnt, tstart, aux);
        scanB<<<1, 256, 0, stream>>>(aux, tstart);
        scanC<<<GC / 256, 256, 0, stream>>>(tstart, aux, cursor);
        reorder_kernel<<<pblocks, 256, 0, stream>>>(x, v, C, st, cursor, payload, n);
        p2g_cell<<<GC / 256, 256, 0, stream>>>(payload, tstart, grid);
        // grid normalize/gravity/boundary fused into p2g_cell
    } else {
        hipMemsetAsync(grid, 0, grid_bytes, stream);
        p2g_naive<<<pblocks, 256, 0, stream>>>(x, v, C, st, grid, n);
        grid_kernel<<<GC / 256, 256, 0, stream>>>(grid);
    }

    g2p_kernel<<<pblocks, 256, 0, stream>>>(x, F, grid, out_x, out_v, out_C, out_F, n);
}

// Round 5
// 430.626 us; speedup vs baseline: 7.2425x; 7.2425x over previous
//
#include <hip/hip_runtime.h>
#include <math.h>

namespace {
constexpr int   NG    = 64;
constexpr int   GC    = NG * NG * NG;
constexpr int   BOUND = 3;
constexpr float DXf    = 1.0f / 64.0f;
constexpr float INV_DX = 64.0f;
constexpr float DTf    = 5e-4f;
constexpr double P_VOL_D = (0.5 / 64.0) * (0.5 / 64.0) * (0.5 / 64.0);
constexpr float P_MASS_F = (float)(P_VOL_D * 1000.0);
constexpr float AFFINE_SCALE = (float)(-5e-4 * P_VOL_D * 4.0 * 64.0 * 64.0);
constexpr float D_INV  = 4.0f * 64.0f * 64.0f;   // 16384
constexpr float GRAV_Y = -9.8f;

__device__ __forceinline__ void atom_add_f32(float* p, float v) {
    unsafeAtomicAdd(p, v);   // hw global_atomic_add_f32, fire-and-forget
}

__device__ __forceinline__ void weights_of(float fx0, float fx1, float fx2, float w[3][3]) {
    w[0][0] = 0.5f*(1.5f-fx0)*(1.5f-fx0); w[0][1] = 0.5f*(1.5f-fx1)*(1.5f-fx1); w[0][2] = 0.5f*(1.5f-fx2)*(1.5f-fx2);
    w[1][0] = 0.75f-(fx0-1.0f)*(fx0-1.0f); w[1][1] = 0.75f-(fx1-1.0f)*(fx1-1.0f); w[1][2] = 0.75f-(fx2-1.0f)*(fx2-1.0f);
    w[2][0] = 0.5f*(fx0-0.5f)*(fx0-0.5f); w[2][1] = 0.5f*(fx1-0.5f)*(fx1-0.5f); w[2][2] = 0.5f*(fx2-0.5f)*(fx2-0.5f);
}

// quadratic B-spline weight at signed offset u; 0 outside |u|<1.5.
// Bit-exact equal to the reference per-offset formulas for u = fx - o
// (fx and u are both exact multiples of 2^-18 < 2, so all subtractions
// of small integers are exact; branch edges at |u|=0.5 agree exactly).
__device__ __forceinline__ float bspline_w(float u) {
    float au = fabsf(u);
    float a  = 1.5f - au;
    float w  = (au < 0.5f) ? (0.75f - u * u) : (0.5f * a * a);
    return (au < 1.5f) ? w : 0.f;
}
}

// ---------------- pass 1: histogram particles into CELLS (262144 bins) -------
__global__ __launch_bounds__(256) void count_kernel(const float* __restrict__ x,
                                                    int* __restrict__ cnt, int n)
{
    int p = blockIdx.x * 256 + threadIdx.x;
    if (p >= n) return;
    float u0 = x[3*p] * INV_DX, u1 = x[3*p+1] * INV_DX, u2 = x[3*p+2] * INV_DX;
    int b0 = (int)floorf(u0 - 0.5f), b1 = (int)floorf(u1 - 0.5f), b2 = (int)floorf(u2 - 0.5f);
    if ((unsigned)b0 >= 64u || (unsigned)b1 >= 64u || (unsigned)b2 >= 64u) return;
    atomicAdd(&cnt[((b0 << 6) + b1) * 64 + b2], 1);
}

// ---------------- pass 2a: per-256-block exclusive scan, block totals to aux --
__global__ __launch_bounds__(256) void scanA(const int* __restrict__ cnt,
                                             int* __restrict__ start,
                                             int* __restrict__ aux)
{
    __shared__ int sh[256];
    int tid = threadIdx.x;
    int i = blockIdx.x * 256 + tid;
    int v = cnt[i];
    sh[tid] = v;
    __syncthreads();
    for (int off = 1; off < 256; off <<= 1) {
        int t = (tid >= off) ? sh[tid - off] : 0;
        __syncthreads();
        sh[tid] += t;
        __syncthreads();
    }
    start[i] = sh[tid] - v;                 // block-local exclusive
    if (tid == 255) aux[blockIdx.x] = sh[255];
}

// ---------------- pass 2b: scan the 1024 block totals (single block) ---------
__global__ __launch_bounds__(256) void scanB(int* __restrict__ aux,
                                             int* __restrict__ start)
{
    __shared__ int partial[256];
    int tid = threadIdx.x;
    int local[4];
    int s = 0;
#pragma unroll
    for (int i = 0; i < 4; ++i) { local[i] = s; s += aux[tid * 4 + i]; }
    partial[tid] = s;
    __syncthreads();
    for (int off = 1; off < 256; off <<= 1) {
        int v = (tid >= off) ? partial[tid - off] : 0;
        __syncthreads();
        partial[tid] += v;
        __syncthreads();
    }
    int base = (tid > 0) ? partial[tid - 1] : 0;
#pragma unroll
    for (int i = 0; i < 4; ++i) aux[tid * 4 + i] = base + local[i];
    if (tid == 255) start[GC] = partial[255];   // grand total sentinel
}

// ---------------- pass 2c: add block offsets, emit start & cursor ------------
__global__ __launch_bounds__(256) void scanC(int* __restrict__ start,
                                             const int* __restrict__ aux,
                                             int* __restrict__ cursor)
{
    int i = blockIdx.x * 256 + threadIdx.x;
    int v = start[i] + aux[blockIdx.x];
    start[i] = v;
    cursor[i] = v;
}

// ---------------- pass 3: reorder — coalesced read, precompute, payload write
// payload record (64B): [af00,af01,af02,af10][af11,af12,af20,af21][af22,mv0,mv1,mv2][u0,u1,u2,-]
// where u = x*INV_DX is the grid-space position (base+fx combined).
__global__ __launch_bounds__(256) void reorder_kernel(const float* __restrict__ x,
                                                      const float* __restrict__ v,
                                                      const float* __restrict__ C,
                                                      const float* __restrict__ st,
                                                      int* __restrict__ cursor,
                                                      float4* __restrict__ payload, int n)
{
    int p = blockIdx.x * 256 + threadIdx.x;
    if (p >= n) return;

    float u0 = x[3*p] * INV_DX, u1 = x[3*p+1] * INV_DX, u2 = x[3*p+2] * INV_DX;
    int b0 = (int)floorf(u0 - 0.5f), b1 = (int)floorf(u1 - 0.5f), b2 = (int)floorf(u2 - 0.5f);
    if ((unsigned)b0 >= 64u || (unsigned)b1 >= 64u || (unsigned)b2 >= 64u) return;

    float aff[9];
#pragma unroll
    for (int i = 0; i < 9; ++i)
        aff[i] = st[9*p + i] * AFFINE_SCALE + P_MASS_F * C[9*p + i];
    float mv0 = P_MASS_F * v[3*p], mv1 = P_MASS_F * v[3*p+1], mv2 = P_MASS_F * v[3*p+2];

    int pos = atomicAdd(&cursor[((b0 << 6) + b1) * 64 + b2], 1);

    float4* dst = payload + 4 * (size_t)pos;
    dst[0] = make_float4(aff[0], aff[1], aff[2], aff[3]);
    dst[1] = make_float4(aff[4], aff[5], aff[6], aff[7]);
    dst[2] = make_float4(aff[8], mv0, mv1, mv2);
    dst[3] = make_float4(u0, u1, u2, 0.f);
}

// ---------------- pass 4: cell-centric P2G gather — no atomics, no LDS -------
// one thread per grid cell. Cell g gathers particles with base in [g-2,g]^3:
// for each of 9 (o0,o1) rows, the 3 k-neighbors are CONTIGUOUS cell ids, so
// the thread scans one contiguous payload segment per row. Every pair touched
// has nonzero weight (exact 27-cell support; no wasted FLOPs). Grid normalize
// + gravity + boundary are fused here; the cell is owned exclusively -> plain
// float4 store, and the grid array needs no memset.
__global__ __launch_bounds__(256) void p2g_cell(const float4* __restrict__ payload,
                                                const int* __restrict__ start,
                                                float* __restrict__ grid)
{
    int g = blockIdx.x * 256 + threadIdx.x;
    int g0 = g >> 12, g1 = (g >> 6) & 63, g2 = g & 63;
    float fg0 = (float)g0, fg1 = (float)g1, fg2 = (float)g2;

    float acc0 = 0.f, acc1 = 0.f, acc2 = 0.f, acc3 = 0.f;
    int klo = (g2 >= 2) ? g2 - 2 : 0;

#pragma unroll
    for (int o0 = 0; o0 < 3; ++o0) {
        int b0 = g0 - o0;
        if ((unsigned)b0 >= 64u) continue;
#pragma unroll
        for (int o1 = 0; o1 < 3; ++o1) {
            int b1 = g1 - o1;
            if ((unsigned)b1 >= 64u) continue;
            int row = ((b0 << 6) + b1) << 6;
            int s = start[row + klo];
            int e = start[row + g2 + 1];
            for (int idx = s; idx < e; ++idx) {
                const float4* rec = payload + 4 * (size_t)idx;
                float4 r0 = rec[0], r1 = rec[1], r2 = rec[2], r3 = rec[3];
                float u0 = r3.x - fg0, u1 = r3.y - fg1, u2 = r3.z - fg2;
                float w = bspline_w(u0) * bspline_w(u1) * bspline_w(u2);
                float dp0 = -u0 * DXf, dp1 = -u1 * DXf, dp2 = -u2 * DXf;
                acc0 += w * (r2.y + r0.x * dp0 + r0.y * dp1 + r0.z * dp2);
                acc1 += w * (r2.z + r0.w * dp0 + r1.x * dp1 + r1.y * dp2);
                acc2 += w * (r2.w + r1.z * dp0 + r1.w * dp1 + r2.x * dp2);
                acc3 += w * P_MASS_F;
            }
        }
    }

    // fused grid update: normalize, gravity, boundary
    float v0 = 0.f, v1 = 0.f, v2 = 0.f;
    if (acc3 > 0.f) {
        float mm = fmaxf(acc3, 1e-10f);
        v0 = acc0 / mm;
        v1 = acc1 / mm + DTf * GRAV_Y;
        v2 = acc2 / mm;
    }
    if ((g0 < BOUND && v0 < 0.f) || (g0 >= NG - BOUND && v0 > 0.f)) v0 = 0.f;
    if ((g1 < BOUND && v1 < 0.f) || (g1 >= NG - BOUND && v1 > 0.f)) v1 = 0.f;
    if ((g2 < BOUND && v2 < 0.f) || (g2 >= NG - BOUND && v2 > 0.f)) v2 = 0.f;
    ((float4*)grid)[g] = make_float4(v0, v1, v2, acc3);
}

// ---------------- fallback P2G: direct global atomics ----------------
__global__ __launch_bounds__(256) void p2g_naive(const float* __restrict__ x,
                                                 const float* __restrict__ v,
                                                 const float* __restrict__ C,
                                                 const float* __restrict__ st,
                                                 float* __restrict__ grid, int n)
{
    int p = blockIdx.x * 256 + threadIdx.x;
    if (p >= n) return;

    float xp0 = x[3*p], xp1 = x[3*p+1], xp2 = x[3*p+2];
    float u0 = xp0 * INV_DX, u1 = xp1 * INV_DX, u2 = xp2 * INV_DX;
    float b0f = floorf(u0 - 0.5f), b1f = floorf(u1 - 0.5f), b2f = floorf(u2 - 0.5f);
    int base0 = (int)b0f, base1 = (int)b1f, base2 = (int)b2f;
    float fx0 = u0 - b0f, fx1 = u1 - b1f, fx2 = u2 - b2f;

    float w[3][3];
    weights_of(fx0, fx1, fx2, w);

    float aff[3][3];
#pragma unroll
    for (int i = 0; i < 3; ++i)
#pragma unroll
        for (int j = 0; j < 3; ++j)
            aff[i][j] = st[9*p + 3*i + j] * AFFINE_SCALE + P_MASS_F * C[9*p + 3*i + j];

    float mv0 = P_MASS_F * v[3*p], mv1 = P_MASS_F * v[3*p+1], mv2 = P_MASS_F * v[3*p+2];

#pragma unroll
    for (int i = 0; i < 3; ++i) {
        float dp0 = ((float)i - fx0) * DXf;
#pragma unroll
        for (int j = 0; j < 3; ++j) {
            float dp1 = ((float)j - fx1) * DXf;
            float wij = w[i][0] * w[j][1];
            float m0 = mv0 + aff[0][0]*dp0 + aff[0][1]*dp1;
            float m1 = mv1 + aff[1][0]*dp0 + aff[1][1]*dp1;
            float m2 = mv2 + aff[2][0]*dp0 + aff[2][1]*dp1;
            int cellij = ((base0 + i) * NG + (base1 + j)) * NG + base2;
#pragma unroll
            for (int k = 0; k < 3; ++k) {
                float dp2 = ((float)k - fx2) * DXf;
                float wi = wij * w[k][2];
                float* cptr = grid + 4 * (cellij + k);
                atom_add_f32(cptr + 0, wi * (m0 + aff[0][2]*dp2));
                atom_add_f32(cptr + 1, wi * (m1 + aff[1][2]*dp2));
                atom_add_f32(cptr + 2, wi * (m2 + aff[2][2]*dp2));
                atom_add_f32(cptr + 3, wi * P_MASS_F);
            }
        }
    }
}

// ---------------- grid: normalize, gravity, boundary (fallback path only) ----
__global__ __launch_bounds__(256) void grid_kernel(float* __restrict__ grid)
{
    int g = blockIdx.x * 256 + threadIdx.x;
    if (g >= GC) return;
    float4 val = ((const float4*)grid)[g];
    float m = val.w;
    float v0 = 0.f, v1 = 0.f, v2 = 0.f;
    if (m > 0.f) {
        float mm = fmaxf(m, 1e-10f);
        v0 = val.x / mm;
        v1 = val.y / mm + DTf * GRAV_Y;
        v2 = val.z / mm;
    }
    int ci = g >> 12, cj = (g >> 6) & 63, ck = g & 63;
    if ((ci < BOUND && v0 < 0.f) || (ci >= NG - BOUND && v0 > 0.f)) v0 = 0.f;
    if ((cj < BOUND && v1 < 0.f) || (cj >= NG - BOUND && v1 > 0.f)) v1 = 0.f;
    if ((ck < BOUND && v2 < 0.f) || (ck >= NG - BOUND && v2 > 0.f)) v2 = 0.f;
    ((float4*)grid)[g] = make_float4(v0, v1, v2, m);
}

// ---------------- G2P: gather, advect, update C/F ----------------
__global__ __launch_bounds__(256) void g2p_kernel(const float* __restrict__ x,
                                                  const float* __restrict__ F,
                                                  const float* __restrict__ grid,
                                                  float* __restrict__ out_x,
                                                  float* __restrict__ out_v,
                                                  float* __restrict__ out_C,
                                                  float* __restrict__ out_F,
                                                  int n)
{
    int p = blockIdx.x * 256 + threadIdx.x;
    if (p >= n) return;

    float xp0 = x[3*p], xp1 = x[3*p+1], xp2 = x[3*p+2];
    float t0 = xp0 * INV_DX, t1 = xp1 * INV_DX, t2 = xp2 * INV_DX;
    float b0 = floorf(t0 - 0.5f), b1 = floorf(t1 - 0.5f), b2 = floorf(t2 - 0.5f);
    int   base0 = (int)b0, base1 = (int)b1, base2 = (int)b2;
    float fx0 = t0 - b0, fx1 = t1 - b1, fx2 = t2 - b2;

    float w[3][3];
    weights_of(fx0, fx1, fx2, w);

    float vn0 = 0.f, vn1 = 0.f, vn2 = 0.f;
    float Cn[3][3] = {};

#pragma unroll
    for (int i = 0; i < 3; ++i) {
        float dp0 = ((float)i - fx0) * DXf;
#pragma unroll
        for (int j = 0; j < 3; ++j) {
            float dp1 = ((float)j - fx1) * DXf;
            float wij = w[i][0] * w[j][1];
            int cellij = ((base0 + i) * NG + (base1 + j)) * NG + base2;
#pragma unroll
            for (int k = 0; k < 3; ++k) {
                float dp2 = ((float)k - fx2) * DXf;
                float wi = wij * w[k][2];
                float4 gv = ((const float4*)grid)[cellij + k];
                vn0 += wi * gv.x; vn1 += wi * gv.y; vn2 += wi * gv.z;
                float wx = wi * gv.x, wy = wi * gv.y, wz = wi * gv.z;
                Cn[0][0] += wx * dp0; Cn[0][1] += wx * dp1; Cn[0][2] += wx * dp2;
                Cn[1][0] += wy * dp0; Cn[1][1] += wy * dp1; Cn[1][2] += wy * dp2;
                Cn[2][0] += wz * dp0; Cn[2][1] += wz * dp1; Cn[2][2] += wz * dp2;
            }
        }
    }

#pragma unroll
    for (int i = 0; i < 3; ++i)
#pragma unroll
        for (int j = 0; j < 3; ++j)
            Cn[i][j] *= D_INV;

    out_x[3*p]   = xp0 + DTf * vn0;
    out_x[3*p+1] = xp1 + DTf * vn1;
    out_x[3*p+2] = xp2 + DTf * vn2;
    out_v[3*p]   = vn0; out_v[3*p+1] = vn1; out_v[3*p+2] = vn2;

    float Fp[3][3];
#pragma unroll
    for (int i = 0; i < 3; ++i)
#pragma unroll
        for (int j = 0; j < 3; ++j)
            Fp[i][j] = F[9*p + 3*i + j];

#pragma unroll
    for (int i = 0; i < 3; ++i) {
#pragma unroll
        for (int k = 0; k < 3; ++k) {
            float acc = Cn[i][0]*Fp[0][k] + Cn[i][1]*Fp[1][k] + Cn[i][2]*Fp[2][k];
            out_F[9*p + 3*i + k] = Fp[i][k] + DTf * acc;
            out_C[9*p + 3*i + k] = Cn[i][k];
        }
    }
}

extern "C" void kernel_launch(void* const* d_in, const int* in_sizes, int n_in,
                              void* d_out, int out_size, void* d_ws, size_t ws_size,
                              hipStream_t stream)
{
    const float* x  = (const float*)d_in[0];
    const float* v  = (const float*)d_in[1];
    const float* C  = (const float*)d_in[2];
    const float* F  = (const float*)d_in[3];
    const float* st = (const float*)d_in[4];
    int n = in_sizes[0] / 3;            // in_sizes are ELEMENT counts (floats)

    const size_t grid_bytes = (size_t)GC * 4 * sizeof(float);          // 4 MiB
    // tables live in the dead out-tail [22n, 22n+tab_ints):
    // cnt(GC) + start(GC+1) + cursor(GC) + aux(1024) = 787,457 ints
    const size_t tab_ints   = 3 * (size_t)GC + 1 + 1024;
    // out_size is an ELEMENT count (same units as in_sizes): out = 24n floats,
    // need payload[6n..22n) + tables -> 22n + tab_ints <= out_size.
    const bool   use_tiled  = ws_size >= grid_bytes &&
                              (size_t)out_size >= 22 * (size_t)n + tab_ints;

    float* grid = (float*)d_ws;

    float* out  = (float*)d_out;
    float* out_x = out;
    float* out_v = out + 3 * (size_t)n;
    float* out_C = out + 6 * (size_t)n;
    float* out_F = out + 15 * (size_t)n;
    // payload (16 floats/particle) lives in out[6n .. 22n) — dead until g2p overwrites
    float4* payload = (float4*)(out + 6 * (size_t)n);
    int* tab    = (int*)(out + 22 * (size_t)n);
    int* cnt    = tab;                       // GC
    int* tstart = tab + GC;                  // GC + 1
    int* cursor = tab + 2 * GC + 1;          // GC
    int* aux    = tab + 3 * GC + 1;          // 1024

    int pblocks = (n + 255) / 256;

    if (use_tiled) {
        hipMemsetAsync(cnt, 0, (size_t)GC * sizeof(int), stream);
        count_kernel<<<pblocks, 256, 0, stream>>>(x, cnt, n);
        scanA<<<GC / 256, 256, 0, stream>>>(cnt, tstart, aux);
        scanB<<<1, 256, 0, stream>>>(aux, tstart);
        scanC<<<GC / 256, 256, 0, stream>>>(tstart, aux, cursor);
        reorder_kernel<<<pblocks, 256, 0, stream>>>(x, v, C, st, cursor, payload, n);
        p2g_cell<<<GC / 256, 256, 0, stream>>>(payload, tstart, grid);
        // grid normalize/gravity/boundary fused into p2g_cell
    } else {
        hipMemsetAsync(grid, 0, grid_bytes, stream);
        p2g_naive<<<pblocks, 256, 0, stream>>>(x, v, C, st, grid, n);
        grid_kernel<<<GC / 256, 256, 0, stream>>>(grid);
    }

    g2p_kernel<<<pblocks, 256, 0, stream>>>(x, F, grid, out_x, out_v, out_C, out_F, n);
}